// Round 15
// baseline (154.116 us; speedup 1.0000x reference)
//
#include <hip/hip_runtime.h>
#include <hip/hip_bf16.h>

typedef unsigned short u16;
typedef __attribute__((ext_vector_type(8))) short short8v;   // 8 bf16 (4 VGPR)
typedef __attribute__((ext_vector_type(4))) short short4v;   // 4 bf16
typedef __attribute__((ext_vector_type(4))) float float4v;   // 4 f32 acc

__device__ inline u16 f2b(float f) {
  __hip_bfloat16 h = __float2bfloat16(f);
  union { __hip_bfloat16 h; u16 s; } u;
  u.h = h;
  return u.s;
}

__device__ inline float b2f(u16 s) {
  union { u16 s[2]; float f; } u;
  u.s[0] = 0; u.s[1] = s;
  return u.f;
}

__device__ inline void gload_lds16(const u16* g, u16* l) {
  __builtin_amdgcn_global_load_lds(
      (const __attribute__((address_space(1))) void*)g,
      (__attribute__((address_space(3))) void*)l, 16, 0, 0);
}

// ---------------------------------------------------------------------------
// merged fp32 -> bf16 conversion: x (nx float4s) then Wq|Wk|Wv (nw each).
// ---------------------------------------------------------------------------
__global__ __launch_bounds__(256)
void cvt_all(const float* __restrict__ x, const float* __restrict__ Wq,
             const float* __restrict__ Wk, const float* __restrict__ Wv,
             u16* __restrict__ xb, u16* __restrict__ wqk, u16* __restrict__ wv,
             int nx, int nw) {
  const int ntot = nx + 3 * nw;
  for (int i = blockIdx.x * blockDim.x + threadIdx.x; i < ntot;
       i += gridDim.x * blockDim.x) {
    const float* src; u16* dst; int off;
    if (i < nx) { src = x; dst = xb; off = i; }
    else {
      int wi = i - nx;
      int w = wi / nw;
      off = wi - w * nw;
      src = (w == 0) ? Wq : (w == 1) ? Wk : Wv;
      dst = (w == 0) ? wqk : (w == 1) ? wqk + 4l * nw : wv;
    }
    float4 v = ((const float4*)src)[off];
    ushort4 o;
    o.x = f2b(v.x); o.y = f2b(v.y); o.z = f2b(v.z); o.w = f2b(v.w);
    ((ushort4*)dst)[off] = o;
  }
}

// ---------------------------------------------------------------------------
// gemm_core (r8-validated loop): C[m][n] = sum_k A[m][k]*B[n][k], both
// row-major K-contiguous. 128x128 tile, BK=64, 4 waves (2x2), 64x64/wave.
// 2-buffer LDS (64 KB -> 2 blocks/CU). Per K-tile: stage(t+1) first ->
// 16 ds_reads in two pinned groups -> lgkmcnt(8) -> 16 MFMA slice0 ->
// lgkmcnt(0) -> 16 MFMA slice1 -> vmcnt(0) -> s_barrier.
// XOR swizzle byte^=(row&7)<<4 via pre-swizzled global source (linear
// global_load_lds dest) + swizzled ds_reads (0 conflicts, verified r3-r14).
// ---------------------------------------------------------------------------
template <typename CT>
__device__ __forceinline__ void gemm_core(
    const u16* __restrict__ A, int lda,
    const u16* __restrict__ B, int ldb,
    CT* __restrict__ C, int ldc, int m0, int n0, int nk) {
  constexpr int A_U16 = 8192;                     // 128 rows x 64 k
  constexpr int TILE_U16 = 16384;
  constexpr int TILE_BYTES = 32768;
  __shared__ __align__(16) u16 lds[2 * TILE_U16]; // 64 KiB

  const int tid  = threadIdx.x;
  const int lane = tid & 63;
  const int wid  = tid >> 6;
  const int wr   = wid >> 1;
  const int wc   = wid & 1;

  const u16* gsrc[8];
  int loff[8];
#pragma unroll
  for (int j = 0; j < 4; ++j) {
    int c = tid + j * 256;                        // A chunks 0..1023
    int r = c >> 3;
    int kg = ((c & 7) ^ (r & 7)) * 8;
    gsrc[j] = A + (long)(m0 + r) * lda + kg;
    loff[j] = c * 8;
  }
#pragma unroll
  for (int j = 0; j < 4; ++j) {
    int c = tid + j * 256;                        // B chunks 0..1023
    int r = c >> 3;
    int kg = ((c & 7) ^ (r & 7)) * 8;
    gsrc[4 + j] = B + (long)(n0 + r) * ldb + kg;
    loff[4 + j] = A_U16 + c * 8;
  }

#define STAGE_ALL(T_, DST_)                                                 \
  {                                                                         \
    _Pragma("unroll")                                                       \
    for (int s = 0; s < 8; ++s)                                             \
      gload_lds16(gsrc[s] + (long)(T_) * 64, (DST_) + loff[s]);             \
  }

  const int kl  = (lane >> 4) * 16;
  const int swz = (lane & 7) << 4;
  const int kx0 = kl ^ swz;
  const int kx1 = (64 + kl) ^ swz;
  const int abase = (wr * 64 + (lane & 15)) * 128;
  const int bbase = 2 * A_U16 + (wc * 64 + (lane & 15)) * 128;

  float4v acc[4][4];
#pragma unroll
  for (int i = 0; i < 4; ++i)
#pragma unroll
    for (int j = 0; j < 4; ++j)
      acc[i][j] = (float4v){0.f, 0.f, 0.f, 0.f};

  STAGE_ALL(0, lds);
  asm volatile("s_waitcnt vmcnt(0)" ::: "memory");
  __builtin_amdgcn_s_barrier();

  for (int t = 0; t < nk; ++t) {
    const char* bb = (const char*)lds + (t & 1) * TILE_BYTES;
    u16* sb = lds + ((t & 1) ^ 1) * TILE_U16;

    if (t + 1 < nk) STAGE_ALL(t + 1, sb);         // issue early: max slack

    short8v a0[4], b0[4], a1[4], b1[4];
#pragma unroll
    for (int mi = 0; mi < 4; ++mi)
      a0[mi] = *(const short8v*)(bb + abase + mi * 2048 + kx0);
#pragma unroll
    for (int ni = 0; ni < 4; ++ni)
      b0[ni] = *(const short8v*)(bb + bbase + ni * 2048 + kx0);
    __builtin_amdgcn_sched_barrier(0);            // pin group order
#pragma unroll
    for (int mi = 0; mi < 4; ++mi)
      a1[mi] = *(const short8v*)(bb + abase + mi * 2048 + kx1);
#pragma unroll
    for (int ni = 0; ni < 4; ++ni)
      b1[ni] = *(const short8v*)(bb + bbase + ni * 2048 + kx1);

    asm volatile("s_waitcnt lgkmcnt(8)" ::: "memory");  // slice0 landed
    __builtin_amdgcn_sched_barrier(0);
    __builtin_amdgcn_s_setprio(1);
#pragma unroll
    for (int mi = 0; mi < 4; ++mi)
#pragma unroll
      for (int ni = 0; ni < 4; ++ni)
        acc[mi][ni] = __builtin_amdgcn_mfma_f32_16x16x32_bf16(
            a0[mi], b0[ni], acc[mi][ni], 0, 0, 0);
    __builtin_amdgcn_s_setprio(0);

    asm volatile("s_waitcnt lgkmcnt(0)" ::: "memory");  // slice1 landed
    __builtin_amdgcn_sched_barrier(0);
    __builtin_amdgcn_s_setprio(1);
#pragma unroll
    for (int mi = 0; mi < 4; ++mi)
#pragma unroll
      for (int ni = 0; ni < 4; ++ni)
        acc[mi][ni] = __builtin_amdgcn_mfma_f32_16x16x32_bf16(
            a1[mi], b1[ni], acc[mi][ni], 0, 0, 0);
    __builtin_amdgcn_s_setprio(0);

    asm volatile("s_waitcnt vmcnt(0)" ::: "memory");  // t+1's stage landed
    __builtin_amdgcn_s_barrier();                     // visible to all waves
  }
#undef STAGE_ALL

  // epilogue: C/D layout col = lane&15, row = (lane>>4)*4 + reg
  const int r0base = m0 + wr * 64 + ((lane >> 4) << 2);
  const int cbase  = n0 + wc * 64 + (lane & 15);
#pragma unroll
  for (int mi = 0; mi < 4; ++mi) {
#pragma unroll
    for (int ni = 0; ni < 4; ++ni) {
      const int r0 = r0base + mi * 16;
      const int cc = cbase + ni * 16;
#pragma unroll
      for (int r = 0; r < 4; ++r) {
        float v = acc[mi][ni][r];
        if constexpr (__is_same(CT, float)) C[(long)(r0 + r) * ldc + cc] = v;
        else                                C[(long)(r0 + r) * ldc + cc] = f2b(v);
      }
    }
  }
}

// ---------------------------------------------------------------------------
// merged qk + vt dispatch, XCD-chunked: wg = (bid&7)*192 + bid>>3 (bijective
// over 1536 = 8 XCDs x 192). Each XCD owns 192 contiguous wg -> a qk wqk
// y-panel is consumed entirely within one XCD's L2 (was replicated x8).
// wg < 1024 : qk = x @ [Wq;Wk]^T  (64x16 tile grid, x fastest)
// wg >= 1024: vt = Wv @ x^T       (8x64 tile grid, x fastest)
// ---------------------------------------------------------------------------
__global__ __launch_bounds__(256, 2)
void gemm_qkvt(const u16* __restrict__ xb, const u16* __restrict__ wqk,
               const u16* __restrict__ wv, u16* __restrict__ qk,
               u16* __restrict__ vt) {
  const int bid = blockIdx.x;
  const int wg  = (bid & 7) * 192 + (bid >> 3);
  if (wg < 1024) {
    gemm_core<u16>(xb, 1024, wqk, 1024, qk, 2048,
                   (wg & 63) * 128, (wg >> 6) * 128, 16);
  } else {
    const int b = wg - 1024;
    gemm_core<u16>(wv, 1024, xb, 1024, vt, 8192,
                   (b & 7) * 128, (b >> 3) * 128, 16);
  }
}

// ---------------------------------------------------------------------------
// S-only dispatch, live tiles only (544 = 4z x 136 triangle), XCD-chunked:
// g = (bid&7)*68 + bid>>3 (bijective over 544 = 8 x 68). Consecutive g are
// y-fast within an x-row -> a chunk's q-panel + <=12 k-panels fit one L2.
// Triangular decode: z = g/136, r = g%136; x : cum[x] > r; y = r - x(x+1)/2.
// (y = x+1 boundary handled in softmax; y > x+1 fully masked.)
// ---------------------------------------------------------------------------
__global__ __launch_bounds__(256, 2)
void gemm_s(const u16* __restrict__ qk, u16* __restrict__ S) {
  const int cum[16] = {1, 3, 6, 10, 15, 21, 28, 36,
                       45, 55, 66, 78, 91, 105, 120, 136};
  const int bid = blockIdx.x;
  const int g = (bid & 7) * 68 + (bid >> 3);
  const int z = g / 136, r = g % 136;
  int x = 0;
  while (r >= cum[x]) ++x;
  const int y = r - (x ? cum[x - 1] : 0);
  const long zo = (long)z * 4194304;               // z * T * 2D
  gemm_core<u16>(qk + zo, 2048, qk + zo + 1024, 2048, S + zo, 2048,
                 x * 128, y * 128, 16);
}

// ---------------------------------------------------------------------------
// masked scaled softmax, in place on bf16 S (one row per block, B*T blocks).
// Row i sees j <= i+1; scale = 1/32. Zero-pads P up to the PV staged extent
// (tile base + 192). For boundary rows (i%128==127, i<1920) the element
// S[i][i+1] lives in the dropped tile (x,x+1): compute it here as a direct
// q[i].k[i+1] fp32 dot (1024 elems, 4/thread) and inject before max/sum.
// ---------------------------------------------------------------------------
__global__ __launch_bounds__(256)
void softmax_kernel(u16* __restrict__ SP, const u16* __restrict__ qk, int T) {
  const int  iz   = blockIdx.x;                   // global row z*T + i
  const int  i    = iz & (T - 1);
  const long base = (long)iz * T;
  const int  nvis = min(i + 2, T);
  const int  capJ = min(T, ((i >> 7) << 7) + 192);  // PV staging extent
  const float scale = 0.03125f;
  const bool brow = ((i & 127) == 127) && (i < T - 128);

  __shared__ float red[4];
  const int wid = threadIdx.x >> 6;

  // boundary score S[i][i+1] (j = i+1 crosses into dropped tile x+1)
  float sb = 0.f;
  if (brow) {
    const u16* qrow = qk + (long)iz * 2048;            // q: cols 0..1023
    const u16* krow = qk + (long)(iz + 1) * 2048 + 1024;  // k of row i+1
    const int c = threadIdx.x * 4;
    short4v qv = *(const short4v*)&qrow[c];
    short4v kv = *(const short4v*)&krow[c];
    float p = 0.f;
#pragma unroll
    for (int e = 0; e < 4; ++e) p += b2f((u16)qv[e]) * b2f((u16)kv[e]);
#pragma unroll
    for (int o = 32; o; o >>= 1) p += __shfl_xor(p, o);
    if ((threadIdx.x & 63) == 0) red[wid] = p;
    __syncthreads();
    sb = red[0] + red[1] + red[2] + red[3];
    __syncthreads();
  }

  const int j0 = threadIdx.x * 8;
  float v[8];
  float m = -INFINITY;
  if (j0 < nvis) {
    short8v raw = *(const short8v*)&SP[base + j0];
#pragma unroll
    for (int e = 0; e < 8; ++e)
      v[e] = (j0 + e < nvis) ? b2f((u16)raw[e]) * scale : -INFINITY;
    if (brow && j0 == i + 1) v[0] = sb * scale;    // inject boundary score
#pragma unroll
    for (int e = 0; e < 8; ++e) m = fmaxf(m, v[e]);
  }
#pragma unroll
  for (int o = 32; o; o >>= 1) m = fmaxf(m, __shfl_xor(m, o));
  if ((threadIdx.x & 63) == 0) red[wid] = m;
  __syncthreads();
  m = fmaxf(fmaxf(red[0], red[1]), fmaxf(red[2], red[3]));
  __syncthreads();

  float s = 0.f;
  if (j0 < nvis) {
#pragma unroll
    for (int e = 0; e < 8; ++e) {
      float p = (j0 + e < nvis) ? __expf(v[e] - m) : 0.f;
      v[e] = p;
      s += p;
    }
  }
#pragma unroll
  for (int o = 32; o; o >>= 1) s += __shfl_xor(s, o);
  if ((threadIdx.x & 63) == 0) red[wid] = s;
  __syncthreads();
  s = red[0] + red[1] + red[2] + red[3];
  const float inv = 1.0f / s;

  if (j0 < capJ) {
    short8v o8;
#pragma unroll
    for (int e = 0; e < 8; ++e)
      o8[e] = (short)f2b((j0 + e < nvis) ? v[e] * inv : 0.f);
    *(short8v*)&SP[base + j0] = o8;
  }
}

// ---------------------------------------------------------------------------
// PV (r13-validated): O_b = P_b V_b, K cap m0+129.  Flat 512-block grid,
// XCD-chunked + pair-balanced decode: wg = (bid&7)*64 + bid>>3 gives each
// XCD a contiguous 64-block chunk (vt B-panels co-XCD); within a chunk,
// l and l+32 (co-resident CU pair) decode to x and 15-x -> pair work
// nk(x)+nk(15-x) ~ 36 uniform.  Bijective over 512.
// ---------------------------------------------------------------------------
__global__ __launch_bounds__(256, 2)
void gemm_pv(const u16* __restrict__ S, const u16* __restrict__ vt,
             float* __restrict__ out, int K) {
  const int bid = blockIdx.x;
  const int wg  = (bid & 7) * 64 + (bid >> 3);
  const int c   = wg >> 6, l = wg & 63;
  const int z   = c >> 1, yhi = c & 1;
  const int h   = l >> 5, mm = (l >> 4) & 1, x4 = l & 15;
  const int x   = h ? 15 - x4 : x4;
  const int y   = yhi * 4 + 2 * h + mm;
  const int m0  = x * 128, n0 = y * 128;
  const int Keff = min(m0 + 129, K);
  gemm_core<float>(S + (long)z * 4194304, 2048,
                   vt + (long)z * 2048, 8192,
                   out + (long)z * 2097152, 1024,
                   m0, n0, (Keff + 63) >> 6);
}

// ---------------------------------------------------------------------------
extern "C" void kernel_launch(void* const* d_in, const int* in_sizes, int n_in,
                              void* d_out, int out_size, void* d_ws, size_t ws_size,
                              hipStream_t stream) {
  const float* x  = (const float*)d_in[0];
  const float* Wq = (const float*)d_in[1];
  const float* Wk = (const float*)d_in[2];
  const float* Wv = (const float*)d_in[3];
  float* out = (float*)d_out;

  const int B = 4, T = 2048, D = 1024;
  const int M = B * T;          // 8192

  char* ws = (char*)d_ws;
  u16* qk  = (u16*)(ws);                      // 32 MiB: [8192][2048], q|k
  u16* vt  = (u16*)(ws + (32l << 20));        // 16 MiB: [1024][8192] d-major
  u16* xb  = (u16*)(ws + (48l << 20));        // 16 MiB
  u16* wqk = (u16*)(ws + (64l << 20));        //  4 MiB: [2048][1024]
  u16* wv  = (u16*)(ws + (68l << 20));        //  2 MiB
  u16* S   = (u16*)(ws + (72l << 20));        // 32 MiB: 4 x [2048][2048] bf16
  // peak: 104 MiB (ws is 256 MiB)

  // fp32 -> bf16, all inputs in one dispatch
  cvt_all<<<2048, 256, 0, stream>>>(x, Wq, Wk, Wv, xb, wqk, wv,
                                    (M * D) / 4, (D * D) / 4);

  // merged qk + vt (1536 blocks = 3 residency rounds), XCD-chunked
  gemm_qkvt<<<1536, 256, 0, stream>>>(xb, wqk, wv, qk, vt);

  // S_b = q_b k_b^T (544 live blocks, XCD-chunked triangular enumeration)
  gemm_s<<<544, 256, 0, stream>>>(qk, S);

  // softmax in place (S -> P), incl. direct boundary-score dot
  softmax_kernel<<<B * T, 256, 0, stream>>>(S, qk, T);

  // O_b = P_b V_b: XCD-chunked + pair-balanced split of 512 tiles
  gemm_pv<<<512, 256, 0, stream>>>(S, vt, out, T);
}

// Round 16
// 142.040 us; speedup vs baseline: 1.0850x; 1.0850x over previous
//
#include <hip/hip_runtime.h>
#include <hip/hip_bf16.h>

typedef unsigned short u16;
typedef __attribute__((ext_vector_type(8))) short short8v;   // 8 bf16 (4 VGPR)
typedef __attribute__((ext_vector_type(4))) short short4v;   // 4 bf16
typedef __attribute__((ext_vector_type(4))) float float4v;   // 4 f32 acc

__device__ inline u16 f2b(float f) {
  __hip_bfloat16 h = __float2bfloat16(f);
  union { __hip_bfloat16 h; u16 s; } u;
  u.h = h;
  return u.s;
}

__device__ inline float b2f(u16 s) {
  union { u16 s[2]; float f; } u;
  u.s[0] = 0; u.s[1] = s;
  return u.f;
}

__device__ inline void gload_lds16(const u16* g, u16* l) {
  __builtin_amdgcn_global_load_lds(
      (const __attribute__((address_space(1))) void*)g,
      (__attribute__((address_space(3))) void*)l, 16, 0, 0);
}

// ---------------------------------------------------------------------------
// merged fp32 -> bf16 conversion: x (nx float4s) then Wq|Wk|Wv (nw each).
// ---------------------------------------------------------------------------
__global__ __launch_bounds__(256)
void cvt_all(const float* __restrict__ x, const float* __restrict__ Wq,
             const float* __restrict__ Wk, const float* __restrict__ Wv,
             u16* __restrict__ xb, u16* __restrict__ wqk, u16* __restrict__ wv,
             int nx, int nw) {
  const int ntot = nx + 3 * nw;
  for (int i = blockIdx.x * blockDim.x + threadIdx.x; i < ntot;
       i += gridDim.x * blockDim.x) {
    const float* src; u16* dst; int off;
    if (i < nx) { src = x; dst = xb; off = i; }
    else {
      int wi = i - nx;
      int w = wi / nw;
      off = wi - w * nw;
      src = (w == 0) ? Wq : (w == 1) ? Wk : Wv;
      dst = (w == 0) ? wqk : (w == 1) ? wqk + 4l * nw : wv;
    }
    float4 v = ((const float4*)src)[off];
    ushort4 o;
    o.x = f2b(v.x); o.y = f2b(v.y); o.z = f2b(v.z); o.w = f2b(v.w);
    ((ushort4*)dst)[off] = o;
  }
}

// ---------------------------------------------------------------------------
// gemm_core (r8-validated loop): C[m][n] = sum_k A[m][k]*B[n][k], both
// row-major K-contiguous. 128x128 tile, BK=64, 4 waves (2x2), 64x64/wave.
// 2-buffer LDS (64 KB -> 2 blocks/CU). Per K-tile: stage(t+1) first ->
// 16 ds_reads in two pinned groups -> lgkmcnt(8) -> 16 MFMA slice0 ->
// lgkmcnt(0) -> 16 MFMA slice1 -> vmcnt(0) -> s_barrier.
// XOR swizzle byte^=(row&7)<<4 via pre-swizzled global source (linear
// global_load_lds dest) + swizzled ds_reads (0 conflicts, verified r3-r15).
// ---------------------------------------------------------------------------
template <typename CT>
__device__ __forceinline__ void gemm_core(
    const u16* __restrict__ A, int lda,
    const u16* __restrict__ B, int ldb,
    CT* __restrict__ C, int ldc, int m0, int n0, int nk) {
  constexpr int A_U16 = 8192;                     // 128 rows x 64 k
  constexpr int TILE_U16 = 16384;
  constexpr int TILE_BYTES = 32768;
  __shared__ __align__(16) u16 lds[2 * TILE_U16]; // 64 KiB

  const int tid  = threadIdx.x;
  const int lane = tid & 63;
  const int wid  = tid >> 6;
  const int wr   = wid >> 1;
  const int wc   = wid & 1;

  const u16* gsrc[8];
  int loff[8];
#pragma unroll
  for (int j = 0; j < 4; ++j) {
    int c = tid + j * 256;                        // A chunks 0..1023
    int r = c >> 3;
    int kg = ((c & 7) ^ (r & 7)) * 8;
    gsrc[j] = A + (long)(m0 + r) * lda + kg;
    loff[j] = c * 8;
  }
#pragma unroll
  for (int j = 0; j < 4; ++j) {
    int c = tid + j * 256;                        // B chunks 0..1023
    int r = c >> 3;
    int kg = ((c & 7) ^ (r & 7)) * 8;
    gsrc[4 + j] = B + (long)(n0 + r) * ldb + kg;
    loff[4 + j] = A_U16 + c * 8;
  }

#define STAGE_ALL(T_, DST_)                                                 \
  {                                                                         \
    _Pragma("unroll")                                                       \
    for (int s = 0; s < 8; ++s)                                             \
      gload_lds16(gsrc[s] + (long)(T_) * 64, (DST_) + loff[s]);             \
  }

  const int kl  = (lane >> 4) * 16;
  const int swz = (lane & 7) << 4;
  const int kx0 = kl ^ swz;
  const int kx1 = (64 + kl) ^ swz;
  const int abase = (wr * 64 + (lane & 15)) * 128;
  const int bbase = 2 * A_U16 + (wc * 64 + (lane & 15)) * 128;

  float4v acc[4][4];
#pragma unroll
  for (int i = 0; i < 4; ++i)
#pragma unroll
    for (int j = 0; j < 4; ++j)
      acc[i][j] = (float4v){0.f, 0.f, 0.f, 0.f};

  STAGE_ALL(0, lds);
  asm volatile("s_waitcnt vmcnt(0)" ::: "memory");
  __builtin_amdgcn_s_barrier();

  for (int t = 0; t < nk; ++t) {
    const char* bb = (const char*)lds + (t & 1) * TILE_BYTES;
    u16* sb = lds + ((t & 1) ^ 1) * TILE_U16;

    if (t + 1 < nk) STAGE_ALL(t + 1, sb);         // issue early: max slack

    short8v a0[4], b0[4], a1[4], b1[4];
#pragma unroll
    for (int mi = 0; mi < 4; ++mi)
      a0[mi] = *(const short8v*)(bb + abase + mi * 2048 + kx0);
#pragma unroll
    for (int ni = 0; ni < 4; ++ni)
      b0[ni] = *(const short8v*)(bb + bbase + ni * 2048 + kx0);
    __builtin_amdgcn_sched_barrier(0);            // pin group order
#pragma unroll
    for (int mi = 0; mi < 4; ++mi)
      a1[mi] = *(const short8v*)(bb + abase + mi * 2048 + kx1);
#pragma unroll
    for (int ni = 0; ni < 4; ++ni)
      b1[ni] = *(const short8v*)(bb + bbase + ni * 2048 + kx1);

    asm volatile("s_waitcnt lgkmcnt(8)" ::: "memory");  // slice0 landed
    __builtin_amdgcn_sched_barrier(0);
    __builtin_amdgcn_s_setprio(1);
#pragma unroll
    for (int mi = 0; mi < 4; ++mi)
#pragma unroll
      for (int ni = 0; ni < 4; ++ni)
        acc[mi][ni] = __builtin_amdgcn_mfma_f32_16x16x32_bf16(
            a0[mi], b0[ni], acc[mi][ni], 0, 0, 0);
    __builtin_amdgcn_s_setprio(0);

    asm volatile("s_waitcnt lgkmcnt(0)" ::: "memory");  // slice1 landed
    __builtin_amdgcn_sched_barrier(0);
    __builtin_amdgcn_s_setprio(1);
#pragma unroll
    for (int mi = 0; mi < 4; ++mi)
#pragma unroll
      for (int ni = 0; ni < 4; ++ni)
        acc[mi][ni] = __builtin_amdgcn_mfma_f32_16x16x32_bf16(
            a1[mi], b1[ni], acc[mi][ni], 0, 0, 0);
    __builtin_amdgcn_s_setprio(0);

    asm volatile("s_waitcnt vmcnt(0)" ::: "memory");  // t+1's stage landed
    __builtin_amdgcn_s_barrier();                     // visible to all waves
  }
#undef STAGE_ALL

  // epilogue: C/D layout col = lane&15, row = (lane>>4)*4 + reg
  const int r0base = m0 + wr * 64 + ((lane >> 4) << 2);
  const int cbase  = n0 + wc * 64 + (lane & 15);
#pragma unroll
  for (int mi = 0; mi < 4; ++mi) {
#pragma unroll
    for (int ni = 0; ni < 4; ++ni) {
      const int r0 = r0base + mi * 16;
      const int cc = cbase + ni * 16;
#pragma unroll
      for (int r = 0; r < 4; ++r) {
        float v = acc[mi][ni][r];
        if constexpr (__is_same(CT, float)) C[(long)(r0 + r) * ldc + cc] = v;
        else                                C[(long)(r0 + r) * ldc + cc] = f2b(v);
      }
    }
  }
}

// ---------------------------------------------------------------------------
// merged qk + vt dispatch, IDENTITY mapping (r14-validated; r15's y-chunk
// regressed: XCD = bid%8 = x%8 already partitions the 16 MB xb into 2 MB
// per-XCD A-panel sets while wqk (4 MB) streams — 6 MB working set/XCD):
// bid < 1024 : qk = x @ [Wq;Wk]^T  (64x16 tile grid, x fastest)
// bid >= 1024: vt = Wv @ x^T       (8x64 tile grid, x fastest)
// 1536 uniform blocks = exactly 3 residency rounds at 2 blocks/CU.
// ---------------------------------------------------------------------------
__global__ __launch_bounds__(256, 2)
void gemm_qkvt(const u16* __restrict__ xb, const u16* __restrict__ wqk,
               const u16* __restrict__ wv, u16* __restrict__ qk,
               u16* __restrict__ vt) {
  const int bid = blockIdx.x;
  if (bid < 1024) {
    gemm_core<u16>(xb, 1024, wqk, 1024, qk, 2048,
                   (bid & 63) * 128, (bid >> 6) * 128, 16);
  } else {
    const int b = bid - 1024;
    gemm_core<u16>(wv, 1024, xb, 1024, vt, 8192,
                   (b & 7) * 128, (b >> 3) * 128, 16);
  }
}

// ---------------------------------------------------------------------------
// S-only dispatch (r15-validated, ~-5us vs r14): live tiles only (544 =
// 4z x 136 triangle), XCD-chunked: g = (bid&7)*68 + bid>>3 (bijective over
// 544 = 8 x 68). Consecutive g are y-fast within an x-row -> a chunk's
// q-panel + successive k-panels stay in one L2.
// Triangular decode: z = g/136, r = g%136; x: first with cum[x] > r.
// (y = x+1 boundary handled in softmax; y > x+1 fully masked.)
// ---------------------------------------------------------------------------
__global__ __launch_bounds__(256, 2)
void gemm_s(const u16* __restrict__ qk, u16* __restrict__ S) {
  const int cum[16] = {1, 3, 6, 10, 15, 21, 28, 36,
                       45, 55, 66, 78, 91, 105, 120, 136};
  const int bid = blockIdx.x;
  const int g = (bid & 7) * 68 + (bid >> 3);
  const int z = g / 136, r = g % 136;
  int x = 0;
  while (r >= cum[x]) ++x;
  const int y = r - (x ? cum[x - 1] : 0);
  const long zo = (long)z * 4194304;               // z * T * 2D
  gemm_core<u16>(qk + zo, 2048, qk + zo + 1024, 2048, S + zo, 2048,
                 x * 128, y * 128, 16);
}

// ---------------------------------------------------------------------------
// masked scaled softmax, in place on bf16 S (one row per block, B*T blocks).
// Row i sees j <= i+1; scale = 1/32. Zero-pads P up to the PV staged extent
// (tile base + 192). For boundary rows (i%128==127, i<1920) the element
// S[i][i+1] lives in the dropped tile (x,x+1): compute it here as a direct
// q[i].k[i+1] fp32 dot (1024 elems, 4/thread) and inject before max/sum.
// ---------------------------------------------------------------------------
__global__ __launch_bounds__(256)
void softmax_kernel(u16* __restrict__ SP, const u16* __restrict__ qk, int T) {
  const int  iz   = blockIdx.x;                   // global row z*T + i
  const int  i    = iz & (T - 1);
  const long base = (long)iz * T;
  const int  nvis = min(i + 2, T);
  const int  capJ = min(T, ((i >> 7) << 7) + 192);  // PV staging extent
  const float scale = 0.03125f;
  const bool brow = ((i & 127) == 127) && (i < T - 128);

  __shared__ float red[4];
  const int wid = threadIdx.x >> 6;

  // boundary score S[i][i+1] (j = i+1 crosses into dropped tile x+1)
  float sb = 0.f;
  if (brow) {
    const u16* qrow = qk + (long)iz * 2048;            // q: cols 0..1023
    const u16* krow = qk + (long)(iz + 1) * 2048 + 1024;  // k of row i+1
    const int c = threadIdx.x * 4;
    short4v qv = *(const short4v*)&qrow[c];
    short4v kv = *(const short4v*)&krow[c];
    float p = 0.f;
#pragma unroll
    for (int e = 0; e < 4; ++e) p += b2f((u16)qv[e]) * b2f((u16)kv[e]);
#pragma unroll
    for (int o = 32; o; o >>= 1) p += __shfl_xor(p, o);
    if ((threadIdx.x & 63) == 0) red[wid] = p;
    __syncthreads();
    sb = red[0] + red[1] + red[2] + red[3];
    __syncthreads();
  }

  const int j0 = threadIdx.x * 8;
  float v[8];
  float m = -INFINITY;
  if (j0 < nvis) {
    short8v raw = *(const short8v*)&SP[base + j0];
#pragma unroll
    for (int e = 0; e < 8; ++e)
      v[e] = (j0 + e < nvis) ? b2f((u16)raw[e]) * scale : -INFINITY;
    if (brow && j0 == i + 1) v[0] = sb * scale;    // inject boundary score
#pragma unroll
    for (int e = 0; e < 8; ++e) m = fmaxf(m, v[e]);
  }
#pragma unroll
  for (int o = 32; o; o >>= 1) m = fmaxf(m, __shfl_xor(m, o));
  if ((threadIdx.x & 63) == 0) red[wid] = m;
  __syncthreads();
  m = fmaxf(fmaxf(red[0], red[1]), fmaxf(red[2], red[3]));
  __syncthreads();

  float s = 0.f;
  if (j0 < nvis) {
#pragma unroll
    for (int e = 0; e < 8; ++e) {
      float p = (j0 + e < nvis) ? __expf(v[e] - m) : 0.f;
      v[e] = p;
      s += p;
    }
  }
#pragma unroll
  for (int o = 32; o; o >>= 1) s += __shfl_xor(s, o);
  if ((threadIdx.x & 63) == 0) red[wid] = s;
  __syncthreads();
  s = red[0] + red[1] + red[2] + red[3];
  const float inv = 1.0f / s;

  if (j0 < capJ) {
    short8v o8;
#pragma unroll
    for (int e = 0; e < 8; ++e)
      o8[e] = (short)f2b((j0 + e < nvis) ? v[e] * inv : 0.f);
    *(short8v*)&SP[base + j0] = o8;
  }
}

// ---------------------------------------------------------------------------
// PV (r13-validated): O_b = P_b V_b, K cap m0+129.  Flat 512-block grid,
// XCD-chunked + pair-balanced decode: wg = (bid&7)*64 + bid>>3 gives each
// XCD a contiguous 64-block chunk (vt B-panels co-XCD); within a chunk,
// l and l+32 (co-resident CU pair) decode to x and 15-x -> pair work
// nk(x)+nk(15-x) ~ 36 uniform.  Bijective over 512.
// ---------------------------------------------------------------------------
__global__ __launch_bounds__(256, 2)
void gemm_pv(const u16* __restrict__ S, const u16* __restrict__ vt,
             float* __restrict__ out, int K) {
  const int bid = blockIdx.x;
  const int wg  = (bid & 7) * 64 + (bid >> 3);
  const int c   = wg >> 6, l = wg & 63;
  const int z   = c >> 1, yhi = c & 1;
  const int h   = l >> 5, mm = (l >> 4) & 1, x4 = l & 15;
  const int x   = h ? 15 - x4 : x4;
  const int y   = yhi * 4 + 2 * h + mm;
  const int m0  = x * 128, n0 = y * 128;
  const int Keff = min(m0 + 129, K);
  gemm_core<float>(S + (long)z * 4194304, 2048,
                   vt + (long)z * 2048, 8192,
                   out + (long)z * 2097152, 1024,
                   m0, n0, (Keff + 63) >> 6);
}

// ---------------------------------------------------------------------------
extern "C" void kernel_launch(void* const* d_in, const int* in_sizes, int n_in,
                              void* d_out, int out_size, void* d_ws, size_t ws_size,
                              hipStream_t stream) {
  const float* x  = (const float*)d_in[0];
  const float* Wq = (const float*)d_in[1];
  const float* Wk = (const float*)d_in[2];
  const float* Wv = (const float*)d_in[3];
  float* out = (float*)d_out;

  const int B = 4, T = 2048, D = 1024;
  const int M = B * T;          // 8192

  char* ws = (char*)d_ws;
  u16* qk  = (u16*)(ws);                      // 32 MiB: [8192][2048], q|k
  u16* vt  = (u16*)(ws + (32l << 20));        // 16 MiB: [1024][8192] d-major
  u16* xb  = (u16*)(ws + (48l << 20));        // 16 MiB
  u16* wqk = (u16*)(ws + (64l << 20));        //  4 MiB: [2048][1024]
  u16* wv  = (u16*)(ws + (68l << 20));        //  2 MiB
  u16* S   = (u16*)(ws + (72l << 20));        // 32 MiB: 4 x [2048][2048] bf16
  // peak: 104 MiB (ws is 256 MiB)

  // fp32 -> bf16, all inputs in one dispatch
  cvt_all<<<2048, 256, 0, stream>>>(x, Wq, Wk, Wv, xb, wqk, wv,
                                    (M * D) / 4, (D * D) / 4);

  // merged qk + vt (1536 blocks = 3 residency rounds), identity mapping
  gemm_qkvt<<<1536, 256, 0, stream>>>(xb, wqk, wv, qk, vt);

  // S_b = q_b k_b^T (544 live blocks, XCD-chunked triangular enumeration)
  gemm_s<<<544, 256, 0, stream>>>(qk, S);

  // softmax in place (S -> P), incl. direct boundary-score dot
  softmax_kernel<<<B * T, 256, 0, stream>>>(S, qk, T);

  // O_b = P_b V_b: XCD-chunked + pair-balanced split of 512 tiles
  gemm_pv<<<512, 256, 0, stream>>>(S, vt, out, T);
}